// Round 9
// baseline (1044.562 us; speedup 1.0000x reference)
//
#include <hip/hip_runtime.h>

typedef unsigned short ushort_t;
typedef unsigned int uint_t;

typedef __bf16 bf16x8 __attribute__((ext_vector_type(8)));
typedef float  floatx4 __attribute__((ext_vector_type(4)));

#define AS3 __attribute__((address_space(3)))
#define AS1 __attribute__((address_space(1)))

// ---------------- dims ----------------
#define BATCH 512
#define D_IN  120000
#define N1P   640   // 600 padded to 5*128
#define N2P   640
#define N3P   320
#define N4P   256
#define N5P   256

// gemm1: tiles 128x320 (4m x 2n = 8), split-K 25 (KCHUNK 4800 = 150 iters of BK=32)
// grid 200 = 8 XCDs * 25, block 512 (8 waves: 4m x 2n, per-wave 32x160)
#define KSPLIT 25
#define KCHUNK 4800

// ---------------- layer-1 partition params ----------------
#define HALF    60000
#define CHW     15000          // build accumulator width (4 phases per half)
#define NREG    1200
#define NB      256            // partition blocks
#define RSTRIDE 6912           // slab slots per region: mean 6000, +11 sigma

// ---------------- workspace layout ----------------
static constexpr long O_W1 = 0;                          // bf16 [640][120000]
static constexpr long SZ_W1 = 640L * 120000 * 2;
static constexpr long O_W2 = O_W1 + SZ_W1;               // f32 [640][640]
static constexpr long SZ_W2 = 640L * 640 * 4;
static constexpr long O_W3 = O_W2 + SZ_W2;               // f32 [320][640]
static constexpr long SZ_W3 = 320L * 640 * 4;
static constexpr long O_W4 = O_W3 + SZ_W3;               // f32 [256][320]
static constexpr long SZ_W4 = 256L * 320 * 4;
static constexpr long O_W5 = O_W4 + SZ_W4;               // f32 [256][256]
static constexpr long SZ_W5 = 256L * 256 * 4;
static constexpr long O_Y1 = O_W5 + SZ_W5;               // f32 [512][640] split-K target
static constexpr long SZ_Y1 = 512L * 640 * 4;
static constexpr long ZERO_OFF = O_W2;                   // zero W2..W5 + y1
static constexpr long ZERO_BYTES = (O_Y1 + SZ_Y1) - O_W2;
static constexpr long O_SCR = O_Y1 + SZ_Y1;              // scratch (partition, then h bufs)
// partition arrays (live only until build_w1 completes)
static constexpr long O_CNT = O_SCR;                         // int [NREG][NB]
static constexpr long O_OFF = O_CNT + (long)NREG * NB * 4;   // int [NB][NREG]
static constexpr long O_TOT = O_OFF + (long)NB * NREG * 4;   // int [NREG]
static constexpr long O_REC = O_TOT + 4800;                  // int2 [NREG][RSTRIDE] = 66.4 MB
// h-buffers alias the same scratch (partition dead before bn_silu writes h1)
static constexpr long O_H1 = O_SCR;                      // f32 [512][640]
static constexpr long O_H2 = O_H1 + 512L * 640 * 4;      // f32 [512][640]
static constexpr long O_Y3 = O_H2 + 512L * 640 * 4;      // f32 [512][320]
static constexpr long O_H3 = O_Y3 + 512L * 320 * 4;      // f32 [512][320]
static constexpr long O_Y4 = O_H3 + 512L * 320 * 4;      // f32 [512][256]
static constexpr long O_H4 = O_Y4 + 512L * 256 * 4;      // f32 [512][256]

// ---------------- helpers ----------------
__device__ __forceinline__ ushort_t f2bf(float f) {
    union { float f; uint_t u; } x;
    x.f = f;
    uint_t u = x.u;
    return (ushort_t)((u + 0x7FFFu + ((u >> 16) & 1u)) >> 16);  // RNE
}
__device__ __forceinline__ uint_t cvt_pk_bf16(float lo, float hi) {
    uint_t r;
    asm("v_cvt_pk_bf16_f32 %0, %1, %2" : "=v"(r) : "v"(lo), "v"(hi));  // RNE pack
    return r;
}
__device__ __forceinline__ float silu_f(float z) {
    return z / (1.f + expf(-z));
}
__device__ __forceinline__ void load16_lds(const void* g, void* l) {
    __builtin_amdgcn_global_load_lds((const AS1 char*)g, (AS3 char*)l, 16, 0, 0);
}

// ---------------- zero workspace (small region only) ----------------
__global__ void zero_f4(float4* __restrict__ p, long n4) {
    long stride = (long)gridDim.x * blockDim.x;
    for (long i = (long)blockIdx.x * blockDim.x + threadIdx.x; i < n4; i += stride)
        p[i] = make_float4(0.f, 0.f, 0.f, 0.f);
}

// ---------------- layer-1 pass A: per-block region histogram (LDS only) ----------------
__global__ __launch_bounds__(512) void hist1(const int* __restrict__ idx, int nnz, int chunk,
                                             int* __restrict__ counts /*[NREG][NB]*/) {
    __shared__ uint_t h[NREG];
    const int b = blockIdx.x, t = threadIdx.x;
    for (int i = t; i < NREG; i += 512) h[i] = 0;
    __syncthreads();
    const int s = b * chunk;
    const int e = min(s + chunk, nnz);
    for (int i = s + t; i < e; i += 512) {
        int r = idx[i];
        int c = idx[nnz + i];
        atomicAdd(&h[r * 2 + (c >= HALF ? 1 : 0)], 1u);
    }
    __syncthreads();
    for (int i = t; i < NREG; i += 512) counts[(long)i * NB + b] = (int)h[i];
}

// ---------------- layer-1 pass B: per-region exclusive scan over block counts ----------------
__global__ __launch_bounds__(NB) void scan1(const int* __restrict__ counts /*[NREG][NB]*/,
                                            int* __restrict__ offs /*[NB][NREG]*/,
                                            int* __restrict__ totals) {
    __shared__ int s[NB];
    const int reg = blockIdx.x, t = threadIdx.x;
    const int v = counts[(long)reg * NB + t];
    s[t] = v;
    __syncthreads();
    for (int o = 1; o < NB; o <<= 1) {
        int x = (t >= o) ? s[t - o] : 0;
        __syncthreads();
        s[t] += x;
        __syncthreads();
    }
    offs[(long)t * NREG + reg] = s[t] - v;  // exclusive prefix
    if (t == NB - 1) totals[reg] = s[t];
}

// ---------------- layer-1 pass C: scatter records into block-private spans ----------------
__global__ __launch_bounds__(512) void scatter1(const int* __restrict__ idx,
                                                const float* __restrict__ vals,
                                                int nnz, int chunk,
                                                const int* __restrict__ offs /*[NB][NREG]*/,
                                                int2* __restrict__ rec) {
    __shared__ int cur[NREG];
    const int b = blockIdx.x, t = threadIdx.x;
    const int* ob = offs + (long)b * NREG;
    for (int i = t; i < NREG; i += 512) cur[i] = i * RSTRIDE + ob[i];
    __syncthreads();
    const int s = b * chunk;
    const int e = min(s + chunk, nnz);
    for (int i = s + t; i < e; i += 512) {
        int r = idx[i];
        int c = idx[nnz + i];
        float v = vals[i];
        int h = (c >= HALF) ? 1 : 0;
        int reg = r * 2 + h;
        int slot = atomicAdd(&cur[reg], 1);  // LDS atomic -> private global slot
        if (slot < (reg + 1) * RSTRIDE)
            rec[slot] = make_int2(c - h * HALF, __float_as_int(v));
    }
}

// ---------------- layer-1 pass D: LDS f32 accumulate, single bf16 writeout ----------------
__global__ __launch_bounds__(512) void build_w1(const int2* __restrict__ rec,
                                                const int* __restrict__ totals,
                                                ushort_t* __restrict__ W) {
    const int bid = blockIdx.x;
    const int r = bid >> 1, h = bid & 1;
    const int t = threadIdx.x;
    ushort_t* dstbase = W + (size_t)r * D_IN + h * HALF;

    if (r >= 600) {  // padding rows: stream zeros
        uint4 z = make_uint4(0, 0, 0, 0);
        for (int j = t * 8; j < HALF; j += 512 * 8) *(uint4*)(dstbase + j) = z;
        return;
    }

    __shared__ int2 lrec[RSTRIDE];  // 55,296 B
    __shared__ float acc[CHW];      // 60,000 B

    const int reg = r * 2 + h;
    const int n = min(totals[reg], RSTRIDE);
    const int2* src = rec + (long)reg * RSTRIDE;
    for (int i = t; i < n; i += 512) lrec[i] = src[i];
    __syncthreads();

#pragma unroll
    for (int ch = 0; ch < 4; ch++) {
        for (int j = t * 4; j < CHW; j += 512 * 4)
            *(float4*)&acc[j] = make_float4(0.f, 0.f, 0.f, 0.f);
        __syncthreads();
        const int base = ch * CHW;
        for (int i = t; i < n; i += 512) {
            int2 e = lrec[i];
            unsigned off = (unsigned)(e.x - base);
            if (off < (unsigned)CHW)
                atomicAdd(&acc[off], __int_as_float(e.y));  // ds_add_f32
        }
        __syncthreads();
        ushort_t* dst = dstbase + base;
        for (int j = t * 8; j < CHW; j += 512 * 8) {
            union { ushort_t us[8]; uint4 v; } u;
#pragma unroll
            for (int k = 0; k < 8; k++) u.us[k] = f2bf(acc[j + k]);
            *(uint4*)(dst + j) = u.v;
        }
        __syncthreads();
    }
}

// ---------------- merged scatter for W2..W5 (one launch) ----------------
__global__ void scatter_all(const int* __restrict__ i2, const float* __restrict__ v2, int n2,
                            const int* __restrict__ i3, const float* __restrict__ v3, int n3,
                            const int* __restrict__ i4, const float* __restrict__ v4, int n4,
                            const int* __restrict__ i5, const float* __restrict__ v5, int n5,
                            float* __restrict__ W2, float* __restrict__ W3,
                            float* __restrict__ W4, float* __restrict__ W5) {
    int i = blockIdx.x * blockDim.x + threadIdx.x;
    if (i < n2) { atomicAdd(&W2[(size_t)i2[i] * 640 + i2[n2 + i]], v2[i]); return; }
    i -= n2;
    if (i < n3) { atomicAdd(&W3[(size_t)i3[i] * 640 + i3[n3 + i]], v3[i]); return; }
    i -= n3;
    if (i < n4) { atomicAdd(&W4[(size_t)i4[i] * 320 + i4[n4 + i]], v4[i]); return; }
    i -= n4;
    if (i < n5) { atomicAdd(&W5[(size_t)i5[i] * 256 + i5[n5 + i]], v5[i]); }
}

// ---------------- GEMM1: y1(512x640,f32) += X(f32 -> bf16 in-kernel) @ W1^T ------------
// L3-traffic-minimized tile: BM=128, BN=320 -> A read 2x (was 5x), B read 4x: 1.11 GB
// total vs 1.84 GB in R8 (gemm1 is L3-BW-bound at ~7.5 TB/s; R7/R8 both fit that model).
// 512 threads = 8 waves (4m x 2n), per-wave 32x160 output = 2x10 frags, 20 MFMA/iter.
// 3-buffer depth-2 pipeline, A-write-one-iter-late; A f32 loads issued BEFORE B gloads so
// the cvt's value-wait (in-order vmcnt) leaves B in flight. B staged as 1536 chunks
// (384 rows, rows 320-383 are never-read pad reading valid workspace bytes) = exactly 3
// chunks/thread -> every wave issues 5 VM ops/iter -> uniform counted vmcnt(5).
// XCD-aware decode; source-side XOR swizzle (0 bank conflicts R4-R8). LDS 96 KB, 1 blk/CU.
__global__ __launch_bounds__(512) void gemm1(const float* __restrict__ X,
                                             const ushort_t* __restrict__ W,
                                             float* __restrict__ Y) {
    __shared__ ushort_t sA[3][4096];    // 128x32 bf16 per buffer (8 KB)
    __shared__ ushort_t sB[3][12288];   // 384x32 bf16 per buffer (24 KB; rows 320+ pad)

    const int b = blockIdx.x;
    const int wrk = (b & 7) * 25 + (b >> 3);    // 200 = 8 XCDs * 25
    const int ksIdx = wrk >> 3;                 // 0..24
    const int tile = wrk & 7;
    const int bm = tile >> 1, bn = tile & 1;
    const int ks = ksIdx * KCHUNK;
    const int iters = KCHUNK / 32;              // 150

    const int t = threadIdx.x;
    const int lane = t & 63;
    const int w = t >> 6;                       // 0..7
    const int wm = w >> 1, wn = w & 1;
    const int i16 = lane & 15;
    const int qk = lane >> 4;

    // A staging: thread t -> chunk t (16B bf16 at byte t*16); row=t>>2, kq swizzled.
    const int rowA = t >> 2;
    const int kqA = (t & 3) ^ ((t >> 3) & 3);
    const float* qa = X + (size_t)(bm * 128 + rowA) * D_IN + ks + kqA * 8;

    // B staging: chunks c = t, t+512, t+1024 (3 per thread, uniform). chunk c: row=c>>2,
    // kq=(c&3)^((c>>3)&3). global_load_lds dest = wave-uniform base + lane*16.
    const int cB1 = t + 512, cB2 = t + 1024;
    const ushort_t* pb0 = W + (size_t)(bn * 320 + rowA) * D_IN + ks + kqA * 8;  // c=t
    const ushort_t* pb1 = W + (size_t)(bn * 320 + (cB1 >> 2)) * D_IN + ks
                            + (((cB1 & 3) ^ ((cB1 >> 3) & 3))) * 8;
    const ushort_t* pb2 = W + (size_t)(bn * 320 + (cB2 >> 2)) * D_IN + ks
                            + (((cB2 & 3) ^ ((cB2 >> 3) & 3))) * 8;

    int aoff[2], boff[10];
#pragma unroll
    for (int mi = 0; mi < 2; mi++) {
        int row = wm * 32 + mi * 16 + i16;
        aoff[mi] = row * 64 + ((qk ^ ((row >> 1) & 3)) << 4);
    }
#pragma unroll
    for (int nf = 0; nf < 10; nf++) {
        int row = wn * 160 + nf * 16 + i16;
        boff[nf] = row * 64 + ((qk ^ ((row >> 1) & 3)) << 4);
    }

#define STAGEB(s) do {                                       \
        load16_lds(pb0, &sB[s][(w * 64) * 8]);               \
        load16_lds(pb1, &sB[s][(w * 64 + 512) * 8]);         \
        load16_lds(pb2, &sB[s][(w * 64 + 1024) * 8]);        \
        pb0 += 32; pb1 += 32; pb2 += 32; } while (0)
#define WRITEA(s, d0, d1) do {                               \
        uint4 u;                                             \
        u.x = cvt_pk_bf16(d0.x, d0.y); u.y = cvt_pk_bf16(d0.z, d0.w); \
        u.z = cvt_pk_bf16(d1.x, d1.y); u.w = cvt_pk_bf16(d1.z, d1.w); \
        *(uint4*)&sA[s][t * 8] = u; } while (0)

    floatx4 acc[2][10] = {};
    float4 p0, p1;   // A(it+1) values, pending conversion
    float4 n0, n1;   // A(it+2) values, in flight

    // prologue: stage(0) and stage(1); A issued before B each stage (in-order vmcnt trick)
    {
        float4 a0, a1;
        a0 = *(const float4*)qa; a1 = *(const float4*)(qa + 4); qa += 32;   // A(0)
        STAGEB(0);                                                          // B(0)
        p0 = *(const float4*)qa; p1 = *(const float4*)(qa + 4); qa += 32;   // A(1)
        STAGEB(1);                                                          // B(1)
        WRITEA(0, a0, a1);                      // compiler waits A(0) (vmcnt(8))
        asm volatile("s_waitcnt vmcnt(5)" ::: "memory");  // B(0) landed; A(1)+B(1) fly
        asm volatile("s_waitcnt lgkmcnt(0)" ::: "memory");
    }
    __builtin_amdgcn_s_barrier();
    __builtin_amdgcn_sched_barrier(0);

    int cb = 0, wb = 1, nb = 2;
    for (int it = 0; it < iters; ++it) {
        if (it + 2 < iters) {          // issue stage(it+2): A f32 -> regs FIRST, then B
            n0 = *(const float4*)qa; n1 = *(const float4*)(qa + 4); qa += 32;
            STAGEB(nb);
        }

        bf16x8 af0 = *(const bf16x8*)((const char*)&sA[cb][0] + aoff[0]);
        bf16x8 af1 = *(const bf16x8*)((const char*)&sA[cb][0] + aoff[1]);
#pragma unroll
        for (int nf = 0; nf < 10; nf++) {
            bf16x8 bv = *(const bf16x8*)((const char*)&sB[cb][0] + boff[nf]);
            acc[0][nf] = __builtin_amdgcn_mfma_f32_16x16x32_bf16(af0, bv, acc[0][nf], 0, 0, 0);
            acc[1][nf] = __builtin_amdgcn_mfma_f32_16x16x32_bf16(af1, bv, acc[1][nf], 0, 0, 0);
        }

        if (it + 1 < iters) {
            WRITEA(wb, p0, p1);        // value-wait on p (oldest) leaves newer ops flying
            p0 = n0; p1 = n1;
            if (it + 2 < iters) {      // B(it+1) landed; this iter's A+B (5 ops) stay out
                asm volatile("s_waitcnt vmcnt(5)" ::: "memory");
            } else {                   // nothing new issued: drain B(it+1)
                asm volatile("s_waitcnt vmcnt(0)" ::: "memory");
            }
            asm volatile("s_waitcnt lgkmcnt(0)" ::: "memory");
            __builtin_amdgcn_s_barrier();
            __builtin_amdgcn_sched_barrier(0);
        }
        int tmp = cb; cb = wb; wb = nb; nb = tmp;   // rotate buffers
    }
#undef STAGEB
#undef WRITEA

    // epilogue: split-K atomic accumulate (C/D: col = lane&15, row = (lane>>4)*4 + reg)
#pragma unroll
    for (int mi = 0; mi < 2; mi++) {
#pragma unroll
        for (int nf = 0; nf < 10; nf++) {
#pragma unroll
            for (int r = 0; r < 4; r++) {
                int row = bm * 128 + wm * 32 + mi * 16 + qk * 4 + r;
                int col = bn * 320 + wn * 160 + nf * 16 + i16;
                atomicAdd(&Y[(size_t)row * N1P + col], acc[mi][nf][r]);
            }
        }
    }
}

// ---------------- BatchNorm (training, biased var) + SiLU, coalesced 64-col tiles --------
__global__ __launch_bounds__(512) void bn_silu(const float* __restrict__ Y, int ld, int realN,
                                               const float* __restrict__ g,
                                               const float* __restrict__ be,
                                               float* __restrict__ H) {
    const int t = threadIdx.x;
    const int sub = t >> 6;          // 0..7
    const int c = t & 63;
    const int col = blockIdx.x * 64 + c;

    float s = 0.f, ss = 0.f;
#pragma unroll 8
    for (int r = sub; r < BATCH; r += 8) {
        float v = Y[(size_t)r * ld + col];
        s += v;
        ss += v * v;
    }
    __shared__ float rs[8][64], rq[8][64], scs[64], shs[64];
    rs[sub][c] = s;
    rq[sub][c] = ss;
    __syncthreads();
    if (t < 64) {
        float S = 0.f, SS = 0.f;
#pragma unroll
        for (int k = 0; k < 8; k++) { S += rs[k][t]; SS += rq[k][t]; }
        float mean = S * (1.f / 512.f);
        float var  = SS * (1.f / 512.f) - mean * mean;
        int cc = blockIdx.x * 64 + t;
        float sc = 0.f, sh = 0.f;
        if (cc < realN) {
            sc = rsqrtf(var + 1e-5f) * g[cc];
            sh = be[cc] - mean * sc;
        }
        scs[t] = sc;
        shs[t] = sh;
    }
    __syncthreads();
    const float sc = scs[c], sh = shs[c];
#pragma unroll 8
    for (int r = sub; r < BATCH; r += 8) {
        float v = Y[(size_t)r * ld + col];
        H[(size_t)r * ld + col] = silu_f(v * sc + sh);  // pad cols -> silu(0)=0
    }
}

// ---------------- small fp32 GEMM: C(512 x N) = A(512 x K) @ W^T(N x K) ----------------
template <int ACT, int GUARD>
__global__ __launch_bounds__(256) void small_gemm(const float* __restrict__ A, int lda,
                                                  const float* __restrict__ W, int ldw,
                                                  const float* __restrict__ bias, int biasN,
                                                  float* __restrict__ out, int ldo, int outN,
                                                  int K) {
    __shared__ float sA[64][20];
    __shared__ float sB[64][20];
    const int t = threadIdx.x;
    const int m0 = blockIdx.x * 64, n0 = blockIdx.y * 64;
    const int ty = t >> 4, tx = t & 15;
    const int lm = t >> 2, lq = t & 3;
    float acc[4][4] = {};

    for (int kt = 0; kt < K; kt += 16) {
        __syncthreads();
        float4 av = *(const float4*)&A[(size_t)(m0 + lm) * lda + kt + lq * 4];
        float4 wv = *(const float4*)&W[(size_t)(n0 + lm) * ldw + kt + lq * 4];
        sA[lm][lq * 4 + 0] = av.x; sA[lm][lq * 4 + 1] = av.y;
        sA[lm][lq * 4 + 2] = av.z; sA[lm][lq * 4 + 3] = av.w;
        sB[lm][lq * 4 + 0] = wv.x; sB[lm][lq * 4 + 1] = wv.y;
        sB[lm][lq * 4 + 2] = wv.z; sB[lm][lq * 4 + 3] = wv.w;
        __syncthreads();
#pragma unroll
        for (int kg = 0; kg < 4; kg++) {
            float4 a4[4], b4[4];
#pragma unroll
            for (int i = 0; i < 4; i++) a4[i] = *(const float4*)&sA[ty * 4 + i][kg * 4];
#pragma unroll
            for (int j = 0; j < 4; j++) b4[j] = *(const float4*)&sB[tx * 4 + j][kg * 4];
#pragma unroll
            for (int i = 0; i < 4; i++)
#pragma unroll
                for (int j = 0; j < 4; j++)
                    acc[i][j] += a4[i].x * b4[j].x + a4[i].y * b4[j].y +
                                 a4[i].z * b4[j].z + a4[i].w * b4[j].w;
        }
    }

#pragma unroll
    for (int i = 0; i < 4; i++) {
#pragma unroll
        for (int j = 0; j < 4; j++) {
            int row = m0 + ty * 4 + i;
            int col = n0 + tx * 4 + j;
            float v = acc[i][j];
            if (bias != nullptr && col < biasN) v += bias[col];
            if (ACT == 1) v = silu_f(v);
            if (GUARD) {
                if (col < outN) out[(size_t)row * ldo + col] = v;
            } else {
                out[(size_t)row * ldo + col] = v;
            }
        }
    }
}

// ---------------- launch ----------------
extern "C" void kernel_launch(void* const* d_in, const int* in_sizes, int n_in,
                              void* d_out, int out_size, void* d_ws, size_t ws_size,
                              hipStream_t stream) {
    const float* x   = (const float*)d_in[0];
    const int* idx1 = (const int*)d_in[1];  const float* val1 = (const float*)d_in[2];
    const int* idx2 = (const int*)d_in[4];  const float* val2 = (const float*)d_in[5];
    const float* b2 = (const float*)d_in[6];
    const int* idx3 = (const int*)d_in[7];  const float* val3 = (const float*)d_in[8];
    const int* idx4 = (const int*)d_in[10]; const float* val4 = (const float*)d_in[11];
    const int* idx5 = (const int*)d_in[13]; const float* val5 = (const float*)d_in[14];
    const float* b5 = (const float*)d_in[15];
    const float* g1 = (const float*)d_in[16]; const float* be1 = (const float*)d_in[17];
    const float* g2 = (const float*)d_in[18]; const float* be2 = (const float*)d_in[19];
    const float* g3 = (const float*)d_in[20]; const float* be3 = (const float*)d_in[21];

    const int nnz1 = in_sizes[1] / 2;
    const int nnz2 = in_sizes[4] / 2;
    const int nnz3 = in_sizes[7] / 2;
    const int nnz4 = in_sizes[10] / 2;
    const int nnz5 = in_sizes[13] / 2;

    char* ws = (char*)d_ws;
    ushort_t* W1 = (ushort_t*)(ws + O_W1);
    float* W2 = (float*)(ws + O_W2);
    float* W3 = (float*)(ws + O_W3);
    float* W4 = (float*)(ws + O_W4);
    float* W5 = (float*)(ws + O_W5);
    float* y1 = (float*)(ws + O_Y1);
    int*   cnt = (int*)(ws + O_CNT);
    int*   off = (int*)(ws + O_OFF);
    int*   tot = (int*)(ws + O_TOT);
    int2*  rec = (int2*)(ws + O_REC);
    float* h1 = (float*)(ws + O_H1);
    float* h2 = (float*)(ws + O_H2);
    float* y3 = (float*)(ws + O_Y3);
    float* h3 = (float*)(ws + O_H3);
    float* y4 = (float*)(ws + O_Y4);
    float* h4 = (float*)(ws + O_H4);

    // 1) zero W2..W5 + y1 (4.4 MB; W1 not pre-zeroed)
    zero_f4<<<dim3((unsigned)(ZERO_BYTES / 16 / 256 + 1)), dim3(256), 0, stream>>>(
        (float4*)(ws + ZERO_OFF), ZERO_BYTES / 16);

    // 2) layer-1 partition: histogram -> scan -> block-private scatter -> build
    {
        const int chunk = (nnz1 + NB - 1) / NB;
        hist1<<<dim3(NB), dim3(512), 0, stream>>>(idx1, nnz1, chunk, cnt);
        scan1<<<dim3(NREG), dim3(NB), 0, stream>>>(cnt, off, tot);
        scatter1<<<dim3(NB), dim3(512), 0, stream>>>(idx1, val1, nnz1, chunk, off, rec);
        build_w1<<<dim3(640 * 2), dim3(512), 0, stream>>>(rec, tot, W1);
    }

    // 3) densify small weights (one launch)
    {
        int ntot = nnz2 + nnz3 + nnz4 + nnz5;
        scatter_all<<<dim3((ntot + 255) / 256), dim3(256), 0, stream>>>(
            idx2, val2, nnz2, idx3, val3, nnz3, idx4, val4, nnz4, idx5, val5, nnz5,
            W2, W3, W4, W5);
    }

    // 4) layer 1: fused-cast MFMA GEMM, 128x320 tiles, split-K 25, XCD + counted vmcnt
    gemm1<<<dim3(8 * KSPLIT), dim3(512), 0, stream>>>(x, W1, y1);

    // 5) BN1 + silu (b1 cancels inside BN)
    bn_silu<<<dim3(N1P / 64), dim3(512), 0, stream>>>(y1, N1P, 600, g1, be1, h1);

    // 6) layer 2: silu(h1 @ W2^T + b2)
    small_gemm<1, 0><<<dim3(8, N2P / 64), dim3(256), 0, stream>>>(h1, N1P, W2, 640, b2, 600,
                                                                  h2, N2P, N2P, 640);
    // 7) layer 3 + BN2 + silu (b3 cancels)
    small_gemm<0, 0><<<dim3(8, N3P / 64), dim3(256), 0, stream>>>(h2, N2P, W3, 640, nullptr, 0,
                                                                  y3, N3P, N3P, 640);
    bn_silu<<<dim3(N3P / 64), dim3(512), 0, stream>>>(y3, N3P, 300, g2, be2, h3);

    // 8) layer 4 + BN3 + silu (b4 cancels)
    small_gemm<0, 0><<<dim3(8, N4P / 64), dim3(256), 0, stream>>>(h3, N3P, W4, 320, nullptr, 0,
                                                                  y4, N4P, N4P, 320);
    bn_silu<<<dim3(N4P / 64), dim3(512), 0, stream>>>(y4, N4P, 200, g3, be3, h4);

    // 9) layer 5: h4 @ W5^T + b5 -> d_out (fp32, compact 512x200)
    small_gemm<0, 1><<<dim3(8, N5P / 64), dim3(256), 0, stream>>>(h4, N4P, W5, 256, b5, 200,
                                                                  (float*)d_out, 200, 200, 256);
    (void)n_in; (void)out_size; (void)ws_size;
}